// Round 1
// baseline (622.264 us; speedup 1.0000x reference)
//
#include <hip/hip_runtime.h>
#include <stdint.h>

#define BATCH 32
#define NCH 84
#define NA 8400
#define NCLS 80
#define TOPK 1000
#define MAXDET 300
#define CONF 0.25f
#define IOU_T 0.7f
#define MAX_WH 7680.0f
#define IMG_SZ 640.0f

__device__ __constant__ float coco_map_f[NCLS] = {
    1,2,3,4,5,6,7,8,9,10,11,13,14,15,16,17,18,19,20,21,22,23,24,25,27,28,
    31,32,33,34,35,36,37,38,39,40,41,42,43,44,46,47,48,49,50,51,52,53,54,
    55,56,57,58,59,60,61,62,63,64,65,67,70,72,73,74,75,76,77,78,79,80,81,
    82,84,85,86,87,88,89,90};

// ---------------- K1: decode anchors -> key / box / label --------------------
__global__ void decode_kernel(const float* __restrict__ preds,
                              unsigned long long* __restrict__ keys,
                              float4* __restrict__ boxes,
                              int* __restrict__ labels) {
    int gid = blockIdx.x * blockDim.x + threadIdx.x;
    if (gid >= BATCH * NA) return;
    int b = gid / NA;
    int a = gid - b * NA;
    const float* p = preds + (size_t)b * NCH * NA + a;

    float x = p[0];
    float y = p[(size_t)1 * NA];
    float w = p[(size_t)2 * NA];
    float h = p[(size_t)3 * NA];

    float best = p[(size_t)4 * NA];
    int bl = 0;
    for (int c = 1; c < NCLS; ++c) {
        float v = p[(size_t)(4 + c) * NA];
        if (v > best) { best = v; bl = c; }   // strict > : first-index argmax
    }

    // box_xywh = p[..,:4] * 640 ; xyxy = [xy - wh*0.5, xy + wh*0.5]
    float fx = x * IMG_SZ, fy = y * IMG_SZ, fw = w * IMG_SZ, fh = h * IMG_SZ;
    float hw = fw * 0.5f, hh = fh * 0.5f;
    float4 bx = make_float4(fx - hw, fy - hh, fx + hw, fy + hh);

    float s = (best > CONF) ? best : -1.0f;   // conf mask before top_k
    unsigned int fb = __float_as_uint(s);
    unsigned int u = (fb & 0x80000000u) ? ~fb : (fb | 0x80000000u); // sortable
    unsigned long long key =
        ((unsigned long long)u << 32) |
        (unsigned long long)(0xFFFFFFFFu - (unsigned int)a);       // stable tiebreak

    keys[gid]  = key;
    boxes[gid] = bx;
    labels[gid] = bl;
}

// ---------------- bitonic sort, 1024 u64 keys, descending --------------------
__device__ inline void bitonic_sort_desc_1024(unsigned long long* skey, int t) {
    for (int size = 2; size <= 1024; size <<= 1) {
        for (int stride = size >> 1; stride > 0; stride >>= 1) {
            __syncthreads();
            for (int k = t; k < 1024; k += 256) {
                int j = k ^ stride;
                if (j > k) {
                    unsigned long long a0 = skey[k], a1 = skey[j];
                    bool desc = ((k & size) == 0);
                    bool sw = desc ? (a0 < a1) : (a0 > a1);
                    if (sw) { skey[k] = a1; skey[j] = a0; }
                }
            }
        }
    }
    __syncthreads();
}

// ---------------- K2: per-batch topk + NMS + output --------------------------
__global__ __launch_bounds__(256)
void select_nms_kernel(const unsigned long long* __restrict__ keys,
                       const float4* __restrict__ boxes,
                       const int* __restrict__ labels,
                       float* __restrict__ out) {
    const int b = blockIdx.x;
    const int t = threadIdx.x;

    __shared__ unsigned long long skey[1024];       // 8 KB
    __shared__ float rawb[TOPK][4];                 // 16 KB
    __shared__ float offb[TOPK][4];                 // 16 KB
    __shared__ float area_s[TOPK];                  // 4 KB
    __shared__ float sc[TOPK];                      // 4 KB
    __shared__ int   lb[TOPK];                      // 4 KB
    __shared__ unsigned char keep[TOPK];            // 1 KB
    __shared__ unsigned short clist[TOPK];          // 2 KB
    __shared__ int ccnt[NCLS];
    __shared__ int coff[NCLS + 1];
    __shared__ int red[4];
    __shared__ int cnt;

    // ---- load this batch's keys into registers (thread-strided) ----
    unsigned long long kreg[33];
    const unsigned long long* kb = keys + (size_t)b * NA;
    int nk = 0;
    for (int i = t; i < NA; i += 256) kreg[nk++] = kb[i];

    // ---- binary search for the TOPK-th largest key (keys are unique) ----
    unsigned long long T = 0ull;
    for (int bit = 63; bit >= 0; --bit) {
        unsigned long long cand = T | (1ull << bit);
        int c = 0;
        for (int i = 0; i < nk; ++i) c += (kreg[i] >= cand) ? 1 : 0;
        for (int off = 32; off; off >>= 1) c += __shfl_down(c, off, 64);
        if ((t & 63) == 0) red[t >> 6] = c;
        __syncthreads();
        c = red[0] + red[1] + red[2] + red[3];
        if (c >= TOPK) T = cand;
        __syncthreads();
    }

    // ---- compact keys >= T (exactly TOPK of them), then sort descending ----
    if (t == 0) cnt = 0;
    __syncthreads();
    for (int i = 0; i < nk; ++i) {
        if (kreg[i] >= T) {
            int p = atomicAdd(&cnt, 1);
            skey[p] = kreg[i];
        }
    }
    if (t < 24) skey[TOPK + t] = 0ull;   // pad 1000..1023
    __syncthreads();
    bitonic_sort_desc_1024(skey, t);

    // ---- gather payloads for the sorted top-1000 ----
    if (t < NCLS) ccnt[t] = 0;
    __syncthreads();
    for (int j = t; j < TOPK; j += 256) {
        unsigned long long key = skey[j];
        unsigned int a = 0xFFFFFFFFu - (unsigned int)(key & 0xFFFFFFFFull);
        unsigned int u = (unsigned int)(key >> 32);
        unsigned int fbits = (u & 0x80000000u) ? (u ^ 0x80000000u) : ~u;
        float s = __uint_as_float(fbits);
        sc[j] = s;
        int L = labels[(size_t)b * NA + a];
        lb[j] = L;
        float4 bx = boxes[(size_t)b * NA + a];
        rawb[j][0] = bx.x; rawb[j][1] = bx.y; rawb[j][2] = bx.z; rawb[j][3] = bx.w;
        float off = (float)L * MAX_WH;
        float ox0 = bx.x + off, oy0 = bx.y + off, ox1 = bx.z + off, oy1 = bx.w + off;
        offb[j][0] = ox0; offb[j][1] = oy0; offb[j][2] = ox1; offb[j][3] = oy1;
        area_s[j] = (ox1 - ox0) * (oy1 - oy0);   // ref computes area on offset boxes
        keep[j] = 1;
        atomicAdd(&ccnt[L], 1);
    }
    __syncthreads();

    // ---- per-class ordered lists (classes are exactly independent under
    //      MAX_WH offset: cross-class IoU == 0, so greedy NMS decomposes) ----
    if (t == 0) {
        int s0 = 0;
        for (int c = 0; c < NCLS; ++c) { coff[c] = s0; s0 += ccnt[c]; }
        coff[NCLS] = s0;
    }
    __syncthreads();
    if (t < NCLS) {
        int w = coff[t];
        for (int j = 0; j < TOPK; ++j)
            if (lb[j] == t) clist[w++] = (unsigned short)j;
    }
    __syncthreads();

    // ---- greedy NMS, one thread per class, no barriers inside ----
    if (t < NCLS) {
        int s0 = coff[t];
        int n  = coff[t + 1] - s0;
        for (int i = 0; i < n; ++i) {
            int ji = clist[s0 + i];
            if (!keep[ji]) continue;
            float ax0 = offb[ji][0], ay0 = offb[ji][1];
            float ax1 = offb[ji][2], ay1 = offb[ji][3];
            float aa = area_s[ji];
            for (int k2 = i + 1; k2 < n; ++k2) {
                int jk = clist[s0 + k2];
                if (!keep[jk]) continue;
                float lx = fmaxf(ax0, offb[jk][0]);
                float ly = fmaxf(ay0, offb[jk][1]);
                float rx = fminf(ax1, offb[jk][2]);
                float ry = fminf(ay1, offb[jk][3]);
                float w = fmaxf(rx - lx, 0.0f);
                float h = fmaxf(ry - ly, 0.0f);
                float inter = w * h;
                float denom = aa + area_s[jk];
                denom = denom - inter;
                denom = denom + 1e-7f;
                float iou = inter / denom;
                if (iou > IOU_T) keep[jk] = 0;
            }
        }
    }
    __syncthreads();

    // ---- final top-300: key2 = sortable(fin_s) | (stable pos tiebreak) ----
    for (int j = t; j < 1024; j += 256) {
        unsigned long long k2;
        if (j < TOPK) {
            float fs = (keep[j] && sc[j] > CONF) ? sc[j] : -1.0f;
            unsigned int fbits = __float_as_uint(fs);
            unsigned int u = (fbits & 0x80000000u) ? ~fbits : (fbits | 0x80000000u);
            k2 = ((unsigned long long)u << 32) |
                 (unsigned long long)(0xFFFFFFFFu - (unsigned int)j);
        } else {
            k2 = 0ull;
        }
        skey[j] = k2;
    }
    __syncthreads();
    bitonic_sort_desc_1024(skey, t);

    // ---- write outputs: boxes [32,300,4] | scores [32,300] | labels [32,300]
    float* out_boxes  = out;
    float* out_scores = out + (size_t)BATCH * MAXDET * 4;
    float* out_labels = out + (size_t)BATCH * MAXDET * 5;
    for (int r = t; r < MAXDET; r += 256) {
        unsigned long long key = skey[r];
        unsigned int j = 0xFFFFFFFFu - (unsigned int)(key & 0xFFFFFFFFull);
        unsigned int u = (unsigned int)(key >> 32);
        unsigned int fbits = (u & 0x80000000u) ? (u ^ 0x80000000u) : ~u;
        float s = __uint_as_float(fbits);
        bool valid = s > CONF;
        float* ob = out_boxes + ((size_t)b * MAXDET + r) * 4;
        if (valid) {
            ob[0] = rawb[j][0]; ob[1] = rawb[j][1];
            ob[2] = rawb[j][2]; ob[3] = rawb[j][3];
            out_scores[(size_t)b * MAXDET + r] = s;
            out_labels[(size_t)b * MAXDET + r] = coco_map_f[lb[j]];
        } else {
            ob[0] = 0.0f; ob[1] = 0.0f; ob[2] = 0.0f; ob[3] = 0.0f;
            out_scores[(size_t)b * MAXDET + r] = 0.0f;
            out_labels[(size_t)b * MAXDET + r] = 0.0f;
        }
    }
}

// ---------------------------------------------------------------------------
extern "C" void kernel_launch(void* const* d_in, const int* in_sizes, int n_in,
                              void* d_out, int out_size, void* d_ws, size_t ws_size,
                              hipStream_t stream) {
    const float* preds = (const float*)d_in[0];
    char* ws = (char*)d_ws;

    const size_t keys_bytes  = (size_t)BATCH * NA * 8;   // 2,150,400
    const size_t boxes_bytes = (size_t)BATCH * NA * 16;  // 4,300,800

    unsigned long long* keys = (unsigned long long*)ws;
    float4* boxes = (float4*)(ws + keys_bytes);
    int* labels = (int*)(ws + keys_bytes + boxes_bytes);
    float* out = (float*)d_out;

    int total = BATCH * NA;
    decode_kernel<<<(total + 255) / 256, 256, 0, stream>>>(preds, keys, boxes, labels);
    select_nms_kernel<<<BATCH, 256, 0, stream>>>(keys, boxes, labels, out);
}

// Round 3
// 279.615 us; speedup vs baseline: 2.2254x; 2.2254x over previous
//
#include <hip/hip_runtime.h>
#include <stdint.h>

#define BATCH 32
#define NCH 84
#define NA 8400
#define NCLS 80
#define TOPK 1000
#define MAXDET 300
#define CONF 0.25f
#define IOU_T 0.7f
#define MAX_WH 7680.0f
#define IMG_SZ 640.0f

__device__ __constant__ float coco_map_f[NCLS] = {
    1,2,3,4,5,6,7,8,9,10,11,13,14,15,16,17,18,19,20,21,22,23,24,25,27,28,
    31,32,33,34,35,36,37,38,39,40,41,42,43,44,46,47,48,49,50,51,52,53,54,
    55,56,57,58,59,60,61,62,63,64,65,67,70,72,73,74,75,76,77,78,79,80,81,
    82,84,85,86,87,88,89,90};

// ---------------- K1: decode 4 anchors/thread via float4 ---------------------
__global__ __launch_bounds__(256)
void decode_kernel(const float* __restrict__ preds,
                   unsigned long long* __restrict__ keys,
                   float4* __restrict__ boxes,
                   int* __restrict__ labels) {
    const int QPB = NA / 4;                       // 2100 quads per batch
    int gid = blockIdx.x * 256 + threadIdx.x;
    if (gid >= BATCH * QPB) return;
    int b = gid / QPB;
    int q = gid - b * QPB;
    int a0 = q * 4;
    const float* p = preds + (size_t)b * NCH * NA + a0;

    float4 x = *(const float4*)(p);
    float4 y = *(const float4*)(p + NA);
    float4 w = *(const float4*)(p + 2 * NA);
    float4 h = *(const float4*)(p + 3 * NA);

    float4 best = *(const float4*)(p + 4 * NA);
    int lx = 0, ly = 0, lz = 0, lw = 0;
#pragma unroll 4
    for (int c = 1; c < NCLS; ++c) {
        const float4 v = *(const float4*)(p + (size_t)(4 + c) * NA);
        lx = (v.x > best.x) ? c : lx;  best.x = fmaxf(v.x, best.x);
        ly = (v.y > best.y) ? c : ly;  best.y = fmaxf(v.y, best.y);
        lz = (v.z > best.z) ? c : lz;  best.z = fmaxf(v.z, best.z);
        lw = (v.w > best.w) ? c : lw;  best.w = fmaxf(v.w, best.w);
    }

    float bs[4] = {best.x, best.y, best.z, best.w};
    int   bl[4] = {lx, ly, lz, lw};
    float cx[4] = {x.x, x.y, x.z, x.w};
    float cy[4] = {y.x, y.y, y.z, y.w};
    float cw[4] = {w.x, w.y, w.z, w.w};
    float ch[4] = {h.x, h.y, h.z, h.w};

    unsigned long long* kp = keys + (size_t)b * NA + a0;
    float4* bp = boxes + (size_t)b * NA + a0;
    int* lp = labels + (size_t)b * NA + a0;

    float4 obx[4];
    unsigned long long okey[4];
#pragma unroll
    for (int i = 0; i < 4; ++i) {
        float fx = cx[i] * IMG_SZ, fy = cy[i] * IMG_SZ;
        float fw = cw[i] * IMG_SZ, fh = ch[i] * IMG_SZ;
        float hw = fw * 0.5f, hh = fh * 0.5f;
        obx[i] = make_float4(fx - hw, fy - hh, fx + hw, fy + hh);
        float s = (bs[i] > CONF) ? bs[i] : -1.0f;
        unsigned int fb = __float_as_uint(s);
        unsigned int u = (fb & 0x80000000u) ? ~fb : (fb | 0x80000000u);
        okey[i] = ((unsigned long long)u << 32) |
                  (unsigned long long)(0xFFFFFFFFu - (unsigned int)(a0 + i));
    }
#pragma unroll
    for (int i = 0; i < 4; ++i) { kp[i] = okey[i]; bp[i] = obx[i]; }
    *(int4*)lp = make_int4(bl[0], bl[1], bl[2], bl[3]);
}

// ---------------- K2: per-batch radix-select + sort + NMS + output ----------
__global__ __launch_bounds__(1024)
void select_nms_kernel(const unsigned long long* __restrict__ keys,
                       const float4* __restrict__ boxes,
                       const int* __restrict__ labels,
                       float* __restrict__ out) {
    const int b = blockIdx.x;
    const int t = threadIdx.x;

    __shared__ unsigned long long skey[1024];       // 8 KB
    __shared__ float rawb[TOPK][4];                 // 16 KB
    __shared__ float offb[TOPK][4];                 // 16 KB
    __shared__ float area_s[TOPK];                  // 4 KB
    __shared__ int   lb[TOPK];                      // 4 KB
    __shared__ unsigned char keep[TOPK];            // 1 KB
    __shared__ unsigned short clist[TOPK];          // 2 KB
    __shared__ unsigned int cmask[NCLS][32];        // 10 KB
    __shared__ int hist[256];                       // 1 KB
    __shared__ int ccnt[NCLS];
    __shared__ int coff[NCLS + 1];
    __shared__ int selB, selK, cnt, ktot;
    __shared__ int wsum[16], woff[16];

    // ---- load this batch's keys (9 per thread max, stays in VGPRs) ----
    unsigned long long kreg[9];
    const unsigned long long* kb = keys + (size_t)b * NA;
    int nk = 0;
    for (int i = t; i < NA; i += 1024) kreg[nk++] = kb[i];

    // ---- 8-pass MSB-first radix select: exact TOPK-th largest unique key ----
    unsigned long long P = 0ull;
    int k = TOPK;
    for (int d = 7; d >= 0; --d) {
        if (t < 256) hist[t] = 0;
        __syncthreads();
        unsigned long long hi_mask = (d == 7) ? 0ull : (~0ull << (8 * (d + 1)));
        for (int i = 0; i < nk; ++i) {
            unsigned long long key = kreg[i];
            if (((key ^ P) & hi_mask) == 0ull)
                atomicAdd(&hist[(int)((key >> (8 * d)) & 255)], 1);
        }
        __syncthreads();
        if (t == 0) {
            int acc = 0, B = 0, kn = k;
            for (int v = 255; v >= 0; --v) {
                acc += hist[v];
                if (acc >= k) { B = v; kn = k - (acc - hist[v]); break; }
            }
            selB = B; selK = kn;
        }
        __syncthreads();
        P |= ((unsigned long long)selB) << (8 * d);
        k = selK;
    }

    // ---- compact the exactly-TOPK keys >= P, pad, bitonic sort descending ----
    if (t == 0) cnt = 0;
    __syncthreads();
    for (int i = 0; i < nk; ++i) {
        if (kreg[i] >= P) {
            int pos = atomicAdd(&cnt, 1);
            if (pos < 1024) skey[pos] = kreg[i];
        }
    }
    if (t < 1024 - TOPK) skey[TOPK + t] = 0ull;
    __syncthreads();
    for (int size = 2; size <= 1024; size <<= 1) {
        for (int stride = size >> 1; stride > 0; stride >>= 1) {
            int j = t ^ stride;
            if (j > t) {
                unsigned long long a0 = skey[t], a1 = skey[j];
                bool desc = ((t & size) == 0);
                if (desc ? (a0 < a1) : (a0 > a1)) { skey[t] = a1; skey[j] = a0; }
            }
            __syncthreads();
        }
    }

    // ---- gather payloads (sorted rank j = t) ----
    for (int i = t; i < NCLS * 32; i += 1024) ((unsigned int*)cmask)[i] = 0u;
    __syncthreads();
    if (t < TOPK) {
        const int j = t;
        unsigned long long key = skey[j];
        unsigned int a = 0xFFFFFFFFu - (unsigned int)(key & 0xFFFFFFFFull);
        int L = labels[(size_t)b * NA + a];
        lb[j] = L;
        float4 bx = boxes[(size_t)b * NA + a];
        rawb[j][0] = bx.x; rawb[j][1] = bx.y; rawb[j][2] = bx.z; rawb[j][3] = bx.w;
        float off = (float)L * MAX_WH;
        float ox0 = bx.x + off, oy0 = bx.y + off, ox1 = bx.z + off, oy1 = bx.w + off;
        offb[j][0] = ox0; offb[j][1] = oy0; offb[j][2] = ox1; offb[j][3] = oy1;
        area_s[j] = (ox1 - ox0) * (oy1 - oy0);
        keep[j] = 1;
        atomicOr(&cmask[L][j >> 5], 1u << (j & 31));
    }
    __syncthreads();

    // ---- per-class counts / offsets / ordered lists (bitmask popcount rank) --
    if (t < NCLS) {
        int s = 0;
#pragma unroll
        for (int q2 = 0; q2 < 32; ++q2) s += __popc(cmask[t][q2]);
        ccnt[t] = s;
    }
    __syncthreads();
    if (t == 0) {
        int s = 0;
        for (int c = 0; c < NCLS; ++c) { coff[c] = s; s += ccnt[c]; }
        coff[NCLS] = s;
    }
    __syncthreads();
    if (t < TOPK) {
        const int j = t;
        int L = lb[j], w = j >> 5;
        int r = __popc(cmask[L][w] & ((1u << (j & 31)) - 1u));
        for (int q2 = 0; q2 < w; ++q2) r += __popc(cmask[L][q2]);
        clist[coff[L] + r] = (unsigned short)j;
    }
    __syncthreads();

    // ---- greedy NMS, one thread per class (cross-class IoU == 0 exactly) ----
    if (t < NCLS) {
        int s0 = coff[t];
        int n = coff[t + 1] - s0;
        for (int i = 0; i < n; ++i) {
            int ji = clist[s0 + i];
            if (!keep[ji]) continue;
            float ax0 = offb[ji][0], ay0 = offb[ji][1];
            float ax1 = offb[ji][2], ay1 = offb[ji][3];
            float aa = area_s[ji];
            for (int k2 = i + 1; k2 < n; ++k2) {
                int jk = clist[s0 + k2];
                if (!keep[jk]) continue;
                float lx = fmaxf(ax0, offb[jk][0]);
                float ly = fmaxf(ay0, offb[jk][1]);
                float rx = fminf(ax1, offb[jk][2]);
                float ry = fminf(ay1, offb[jk][3]);
                float w = fmaxf(rx - lx, 0.0f);
                float h = fmaxf(ry - ly, 0.0f);
                float inter = w * h;
                float denom = aa + area_s[jk];
                denom = denom - inter;
                denom = denom + 1e-7f;
                if (inter / denom > IOU_T) keep[jk] = 0;
            }
        }
    }
    __syncthreads();

    // ---- kept entries in sorted order ARE top_k(fin_s) order: ballot-scan ----
    bool valid = false;
    float sj = 0.0f;
    if (t < TOPK) {
        unsigned long long key = skey[t];
        unsigned int u = (unsigned int)(key >> 32);
        unsigned int fb = (u & 0x80000000u) ? (u ^ 0x80000000u) : ~u;
        sj = __uint_as_float(fb);
        valid = keep[t] && (sj > CONF);
    }
    unsigned long long m = __ballot(valid);
    int wid = t >> 6, lane = t & 63;
    if (lane == 0) wsum[wid] = __popcll(m);
    __syncthreads();
    if (t == 0) {
        int s = 0;
        for (int q2 = 0; q2 < 16; ++q2) { woff[q2] = s; s += wsum[q2]; }
        ktot = s;
    }
    __syncthreads();
    int rank = woff[wid] + __popcll(m & ((1ull << lane) - 1ull));

    float* out_boxes = out;
    float* out_scores = out + (size_t)BATCH * MAXDET * 4;
    float* out_labels = out + (size_t)BATCH * MAXDET * 5;
    if (valid && rank < MAXDET) {
        float* ob = out_boxes + ((size_t)b * MAXDET + rank) * 4;
        ob[0] = rawb[t][0]; ob[1] = rawb[t][1]; ob[2] = rawb[t][2]; ob[3] = rawb[t][3];
        out_scores[(size_t)b * MAXDET + rank] = sj;
        out_labels[(size_t)b * MAXDET + rank] = coco_map_f[lb[t]];
    }
    if (t < MAXDET && t >= ktot) {
        float* ob = out_boxes + ((size_t)b * MAXDET + t) * 4;
        ob[0] = 0.0f; ob[1] = 0.0f; ob[2] = 0.0f; ob[3] = 0.0f;
        out_scores[(size_t)b * MAXDET + t] = 0.0f;
        out_labels[(size_t)b * MAXDET + t] = 0.0f;
    }
}

// ---------------------------------------------------------------------------
extern "C" void kernel_launch(void* const* d_in, const int* in_sizes, int n_in,
                              void* d_out, int out_size, void* d_ws, size_t ws_size,
                              hipStream_t stream) {
    const float* preds = (const float*)d_in[0];
    char* ws = (char*)d_ws;

    const size_t keys_bytes = (size_t)BATCH * NA * 8;    // 2,150,400
    const size_t boxes_bytes = (size_t)BATCH * NA * 16;  // 4,300,800

    unsigned long long* keys = (unsigned long long*)ws;
    float4* boxes = (float4*)(ws + keys_bytes);
    int* labels = (int*)(ws + keys_bytes + boxes_bytes);
    float* out = (float*)d_out;

    int total = BATCH * (NA / 4);
    decode_kernel<<<(total + 255) / 256, 256, 0, stream>>>(preds, keys, boxes, labels);
    select_nms_kernel<<<BATCH, 1024, 0, stream>>>(keys, boxes, labels, out);
}

// Round 4
// 240.782 us; speedup vs baseline: 2.5843x; 1.1613x over previous
//
#include <hip/hip_runtime.h>
#include <stdint.h>

typedef unsigned long long u64;
typedef unsigned int u32;

#define BATCH 32
#define NCH 84
#define NA 8400
#define NCLS 80
#define TOPK 1000
#define MAXDET 300
#define CONF 0.25f
#define IOU_T 0.7f
#define MAX_WH 7680.0f
#define IMG_SZ 640.0f
#define NT 1024
#define KPT 9            // ceil(NA / NT)
#define NCOPY 8          // privatized histogram copies
#define HPAD 257         // 256 buckets + 1 pad -> copies on distinct banks

__device__ __constant__ float coco_map_f[NCLS] = {
    1,2,3,4,5,6,7,8,9,10,11,13,14,15,16,17,18,19,20,21,22,23,24,25,27,28,
    31,32,33,34,35,36,37,38,39,40,41,42,43,44,46,47,48,49,50,51,52,53,54,
    55,56,57,58,59,60,61,62,63,64,65,67,70,72,73,74,75,76,77,78,79,80,81,
    82,84,85,86,87,88,89,90};

__device__ inline u64 shflx64(u64 v, int m) {
    int lo = __shfl_xor((int)(u32)(v & 0xFFFFFFFFull), m, 64);
    int hi = __shfl_xor((int)(u32)(v >> 32), m, 64);
    return ((u64)(u32)hi << 32) | (u32)lo;
}

// ---------------- K1: decode 2 anchors/thread via float2 ---------------------
__global__ __launch_bounds__(256)
void decode_kernel(const float* __restrict__ preds,
                   u64* __restrict__ keys,
                   float4* __restrict__ boxes,
                   int* __restrict__ labels) {
    const int PPB = NA / 2;                       // 4200 pairs per batch
    int gid = blockIdx.x * 256 + threadIdx.x;
    if (gid >= BATCH * PPB) return;
    int b = gid / PPB;
    int q = gid - b * PPB;
    int a0 = q * 2;
    const float* p = preds + (size_t)b * NCH * NA + a0;

    float2 x = *(const float2*)(p);
    float2 y = *(const float2*)(p + NA);
    float2 w = *(const float2*)(p + 2 * NA);
    float2 h = *(const float2*)(p + 3 * NA);

    float2 best = *(const float2*)(p + 4 * NA);
    int l0 = 0, l1 = 0;
#pragma unroll 16
    for (int c = 1; c < NCLS; ++c) {
        float2 v = *(const float2*)(p + (size_t)(4 + c) * NA);
        l0 = (v.x > best.x) ? c : l0;  best.x = fmaxf(v.x, best.x);
        l1 = (v.y > best.y) ? c : l1;  best.y = fmaxf(v.y, best.y);
    }

    float bs[2] = {best.x, best.y};
    int   bl[2] = {l0, l1};
    float cx[2] = {x.x, x.y};
    float cy[2] = {y.x, y.y};
    float cw[2] = {w.x, w.y};
    float ch[2] = {h.x, h.y};

    u64* kp = keys + (size_t)b * NA + a0;
    float4* bp = boxes + (size_t)b * NA + a0;
    int* lp = labels + (size_t)b * NA + a0;

#pragma unroll
    for (int i = 0; i < 2; ++i) {
        float fx = cx[i] * IMG_SZ, fy = cy[i] * IMG_SZ;
        float fw = cw[i] * IMG_SZ, fh = ch[i] * IMG_SZ;
        float hw = fw * 0.5f, hh = fh * 0.5f;
        bp[i] = make_float4(fx - hw, fy - hh, fx + hw, fy + hh);
        float s = (bs[i] > CONF) ? bs[i] : -1.0f;
        u32 fb = __float_as_uint(s);
        u32 u = (fb & 0x80000000u) ? ~fb : (fb | 0x80000000u);
        // 46-bit key: sortable score bits << 14 | inverted anchor index
        kp[i] = ((u64)u << 14) | (u64)(16383 - (a0 + i));
        lp[i] = bl[i];
    }
}

// ---------------- K2: per-batch radix-select + sort + NMS + output ----------
__global__ __launch_bounds__(NT)
void select_nms_kernel(const u64* __restrict__ keys,
                       const float4* __restrict__ boxes,
                       const int* __restrict__ labels,
                       float* __restrict__ out) {
    const int b = blockIdx.x;
    const int t = threadIdx.x;
    const int lane = t & 63, wid = t >> 6;

    __shared__ u64 skey[NT];                        // 8 KB
    __shared__ float offb[TOPK][4];                 // 16 KB
    __shared__ float area_s[TOPK];                  // 4 KB
    __shared__ unsigned short aid[TOPK];            // 2 KB
    __shared__ unsigned char lb8[TOPK];             // 1 KB
    __shared__ unsigned char keep[TOPK];            // 1 KB
    __shared__ unsigned short clist[TOPK];          // 2 KB
    __shared__ u32 cmask[NCLS][32];                 // 10 KB
    __shared__ int sh_hist[NCOPY * HPAD];           // 8.2 KB
    __shared__ int ccnt[NCLS];
    __shared__ int coff[NCLS + 1];
    __shared__ int selB, selK, cnt, ktot;
    __shared__ int wsum[16], woff[16];

    // ---- load this batch's keys (<=9 per thread, stays in VGPRs) ----
    u64 kreg[KPT];
    const u64* kb = keys + (size_t)b * NA;
    int nk = 0;
    for (int i = t; i < NA; i += NT) kreg[nk++] = kb[i];

    // ---- 6-pass MSB-first radix select over the 46-bit key ----
    u64 P = 0ull;
    int kk = TOPK;
    for (int d = 5; d >= 0; --d) {
        for (int i = t; i < NCOPY * HPAD; i += NT) sh_hist[i] = 0;
        __syncthreads();
        u64 hmask = (~0ull) << (8 * (d + 1));
        int* myh = sh_hist + (wid & (NCOPY - 1)) * HPAD;
        for (int i = 0; i < KPT; ++i) {
            if (i < nk) {
                u64 key = kreg[i];
                if (((key ^ P) & hmask) == 0ull)
                    atomicAdd(&myh[(int)((key >> (8 * d)) & 255)], 1);
            }
        }
        __syncthreads();
        if (t < 64) {
            int h0 = 0, h1 = 0, h2 = 0, h3 = 0;
            for (int c = 0; c < NCOPY; ++c) {
                const int* hp = sh_hist + c * HPAD + 4 * t;
                h0 += hp[0]; h1 += hp[1]; h2 += hp[2]; h3 += hp[3];
            }
            int s = h0 + h1 + h2 + h3;
            // wave suffix-scan (no barriers): S = sum over groups >= t
            int S = s;
            #pragma unroll
            for (int off = 1; off < 64; off <<= 1) {
                int o = __shfl_down(S, off, 64);
                if (t + off < 64) S += o;
            }
            int Snext = S - s;
            int c3 = Snext + h3, c2 = c3 + h2, c1 = c2 + h1, c0 = c1 + h0;
            // largest bucket v with cum[v] >= kk (cum non-increasing in v)
            int cand = -1, above = 0;
            if (c0 >= kk) {
                if      (c3 >= kk) { cand = 4 * t + 3; above = Snext; }
                else if (c2 >= kk) { cand = 4 * t + 2; above = c3; }
                else if (c1 >= kk) { cand = 4 * t + 1; above = c2; }
                else               { cand = 4 * t;     above = c1; }
            }
            int pc = (cand < 0) ? 0 : (((cand + 1) << 16) | (kk - above));
            #pragma unroll
            for (int off = 32; off; off >>= 1)
                pc = max(pc, __shfl_down(pc, off, 64));
            if (t == 0) { selB = (pc >> 16) - 1; selK = pc & 0xFFFF; }
        }
        __syncthreads();
        P |= ((u64)selB) << (8 * d);
        kk = selK;
    }

    // ---- compact the exactly-TOPK keys >= P (wave-aggregated) ----
    if (t == 0) cnt = 0;
    __syncthreads();
    for (int i = 0; i < KPT; ++i) {
        bool p = (i < nk) && (kreg[i] >= P);
        u64 m = __ballot(p);
        int base = 0;
        if (lane == 0) base = atomicAdd(&cnt, (int)__popcll(m));
        base = __shfl(base, 0, 64);
        if (p) skey[base + (int)__popcll(m & ((1ull << lane) - 1ull))] = kreg[i];
    }
    if (t < NT - TOPK) skey[TOPK + t] = 0ull;
    __syncthreads();

    // ---- hybrid bitonic sort, descending: shfl_xor for stride<64 ----
    u64 myk = skey[t];
    for (int size = 2; size <= NT; size <<= 1) {
        bool up = ((t & size) == 0);
        for (int stride = size >> 1; stride; stride >>= 1) {
            u64 pk;
            if (stride >= 64) {
                __syncthreads(); skey[t] = myk; __syncthreads();
                pk = skey[t ^ stride];
            } else {
                pk = shflx64(myk, stride);
            }
            bool tlow = ((t & stride) == 0);
            u64 mn = (myk < pk) ? myk : pk;
            u64 mx = (myk < pk) ? pk : myk;
            myk = up ? (tlow ? mx : mn) : (tlow ? mn : mx);
        }
    }
    __syncthreads();
    skey[t] = myk;
    for (int i = t; i < NCLS * 32; i += NT) ((u32*)cmask)[i] = 0u;
    __syncthreads();

    // ---- gather payloads for sorted rank j = t ----
    if (t < TOPK) {
        const int j = t;
        u64 key = skey[j];
        int a = 16383 - (int)(key & 16383ull);
        aid[j] = (unsigned short)a;
        int L = labels[(size_t)b * NA + a];
        lb8[j] = (unsigned char)L;
        float4 bx = boxes[(size_t)b * NA + a];
        float off = (float)L * MAX_WH;
        float ox0 = bx.x + off, oy0 = bx.y + off, ox1 = bx.z + off, oy1 = bx.w + off;
        offb[j][0] = ox0; offb[j][1] = oy0; offb[j][2] = ox1; offb[j][3] = oy1;
        area_s[j] = (ox1 - ox0) * (oy1 - oy0);   // ref: area on offset boxes
        keep[j] = 1;
        atomicOr(&cmask[L][j >> 5], 1u << (j & 31));
    }
    __syncthreads();

    // ---- per-class counts / offsets / ordered lists (popcount rank) ----
    if (t < NCLS) {
        int s = 0;
#pragma unroll
        for (int q2 = 0; q2 < 32; ++q2) s += __popc(cmask[t][q2]);
        ccnt[t] = s;
    }
    __syncthreads();
    if (t == 0) {
        int s = 0;
        for (int c = 0; c < NCLS; ++c) { coff[c] = s; s += ccnt[c]; }
        coff[NCLS] = s;
    }
    __syncthreads();
    if (t < TOPK) {
        const int j = t;
        int L = lb8[j], w = j >> 5;
        int r = __popc(cmask[L][w] & ((1u << (j & 31)) - 1u));
        for (int q2 = 0; q2 < w; ++q2) r += __popc(cmask[L][q2]);
        clist[coff[L] + r] = (unsigned short)j;
    }
    __syncthreads();

    // ---- greedy NMS, one thread per class (cross-class IoU == 0 exactly) ----
    if (t < NCLS) {
        int s0 = coff[t];
        int n = coff[t + 1] - s0;
        for (int i = 0; i < n; ++i) {
            int ji = clist[s0 + i];
            if (!keep[ji]) continue;
            float ax0 = offb[ji][0], ay0 = offb[ji][1];
            float ax1 = offb[ji][2], ay1 = offb[ji][3];
            float aa = area_s[ji];
            for (int k2 = i + 1; k2 < n; ++k2) {
                int jk = clist[s0 + k2];
                if (!keep[jk]) continue;
                float lx = fmaxf(ax0, offb[jk][0]);
                float ly = fmaxf(ay0, offb[jk][1]);
                float rx = fminf(ax1, offb[jk][2]);
                float ry = fminf(ay1, offb[jk][3]);
                float w = fmaxf(rx - lx, 0.0f);
                float h = fmaxf(ry - ly, 0.0f);
                float inter = w * h;
                float denom = aa + area_s[jk];
                denom = denom - inter;
                denom = denom + 1e-7f;
                if (inter / denom > IOU_T) keep[jk] = 0;
            }
        }
    }
    __syncthreads();

    // ---- kept entries in sorted order ARE top_k(fin_s) order: ballot-scan ----
    bool valid = false;
    float sj = 0.0f;
    if (t < TOPK) {
        u32 u = (u32)(skey[t] >> 14);
        u32 fb = (u & 0x80000000u) ? (u ^ 0x80000000u) : ~u;
        sj = __uint_as_float(fb);
        valid = keep[t] && (sj > CONF);
    }
    u64 m = __ballot(valid);
    if (lane == 0) wsum[wid] = (int)__popcll(m);
    __syncthreads();
    if (t == 0) {
        int s = 0;
        for (int q2 = 0; q2 < 16; ++q2) { woff[q2] = s; s += wsum[q2]; }
        ktot = s;
    }
    __syncthreads();
    int rank = woff[wid] + (int)__popcll(m & ((1ull << lane) - 1ull));

    float* out_boxes = out;
    float* out_scores = out + (size_t)BATCH * MAXDET * 4;
    float* out_labels = out + (size_t)BATCH * MAXDET * 5;
    if (valid && rank < MAXDET) {
        float4 bx = boxes[(size_t)b * NA + aid[t]];
        float* ob = out_boxes + ((size_t)b * MAXDET + rank) * 4;
        ob[0] = bx.x; ob[1] = bx.y; ob[2] = bx.z; ob[3] = bx.w;
        out_scores[(size_t)b * MAXDET + rank] = sj;
        out_labels[(size_t)b * MAXDET + rank] = coco_map_f[lb8[t]];
    }
    if (t < MAXDET && t >= ktot) {
        float* ob = out_boxes + ((size_t)b * MAXDET + t) * 4;
        ob[0] = 0.0f; ob[1] = 0.0f; ob[2] = 0.0f; ob[3] = 0.0f;
        out_scores[(size_t)b * MAXDET + t] = 0.0f;
        out_labels[(size_t)b * MAXDET + t] = 0.0f;
    }
}

// ---------------------------------------------------------------------------
extern "C" void kernel_launch(void* const* d_in, const int* in_sizes, int n_in,
                              void* d_out, int out_size, void* d_ws, size_t ws_size,
                              hipStream_t stream) {
    const float* preds = (const float*)d_in[0];
    char* ws = (char*)d_ws;

    const size_t keys_bytes = (size_t)BATCH * NA * 8;    // 2,150,400
    const size_t boxes_bytes = (size_t)BATCH * NA * 16;  // 4,300,800

    u64* keys = (u64*)ws;
    float4* boxes = (float4*)(ws + keys_bytes);
    int* labels = (int*)(ws + keys_bytes + boxes_bytes);
    float* out = (float*)d_out;

    int total = BATCH * (NA / 2);
    decode_kernel<<<(total + 255) / 256, 256, 0, stream>>>(preds, keys, boxes, labels);
    select_nms_kernel<<<BATCH, NT, 0, stream>>>(keys, boxes, labels, out);
}

// Round 5
// 189.373 us; speedup vs baseline: 3.2859x; 1.2715x over previous
//
#include <hip/hip_runtime.h>
#include <stdint.h>

typedef unsigned long long u64;
typedef unsigned int u32;

#define BATCH 32
#define NCH 84
#define NA 8400
#define NCLS 80
#define TOPK 1000
#define MAXDET 300
#define CONF 0.25f
#define IOU_T 0.7f
#define MAX_WH 7680.0f
#define IMG_SZ 640.0f
#define NT 1024
#define KPT 9            // ceil(NA / NT)
#define NCOPY 8          // privatized histogram copies
#define HPAD 260         // 256 buckets + pad: 16B-aligned rows, bank-staggered copies

__device__ __constant__ float coco_map_f[NCLS] = {
    1,2,3,4,5,6,7,8,9,10,11,13,14,15,16,17,18,19,20,21,22,23,24,25,27,28,
    31,32,33,34,35,36,37,38,39,40,41,42,43,44,46,47,48,49,50,51,52,53,54,
    55,56,57,58,59,60,61,62,63,64,65,67,70,72,73,74,75,76,77,78,79,80,81,
    82,84,85,86,87,88,89,90};

__device__ inline u64 shflx64(u64 v, int m) {
    int lo = __shfl_xor((int)(u32)(v & 0xFFFFFFFFull), m, 64);
    int hi = __shfl_xor((int)(u32)(v >> 32), m, 64);
    return ((u64)(u32)hi << 32) | (u32)lo;
}

// ---------------- K1: decode 2 anchors/thread via float2 ---------------------
__global__ __launch_bounds__(256)
void decode_kernel(const float* __restrict__ preds,
                   u64* __restrict__ keys,
                   float4* __restrict__ boxes,
                   int* __restrict__ labels) {
    const int PPB = NA / 2;                       // 4200 pairs per batch
    int gid = blockIdx.x * 256 + threadIdx.x;
    if (gid >= BATCH * PPB) return;
    int b = gid / PPB;
    int q = gid - b * PPB;
    int a0 = q * 2;
    const float* p = preds + (size_t)b * NCH * NA + a0;

    float2 x = *(const float2*)(p);
    float2 y = *(const float2*)(p + NA);
    float2 w = *(const float2*)(p + 2 * NA);
    float2 h = *(const float2*)(p + 3 * NA);

    float2 best = *(const float2*)(p + 4 * NA);
    int l0 = 0, l1 = 0;
#pragma unroll 16
    for (int c = 1; c < NCLS; ++c) {
        float2 v = *(const float2*)(p + (size_t)(4 + c) * NA);
        l0 = (v.x > best.x) ? c : l0;  best.x = fmaxf(v.x, best.x);
        l1 = (v.y > best.y) ? c : l1;  best.y = fmaxf(v.y, best.y);
    }

    float bs[2] = {best.x, best.y};
    int   bl[2] = {l0, l1};
    float cx[2] = {x.x, x.y};
    float cy[2] = {y.x, y.y};
    float cw[2] = {w.x, w.y};
    float ch[2] = {h.x, h.y};

    u64* kp = keys + (size_t)b * NA + a0;
    float4* bp = boxes + (size_t)b * NA + a0;
    int* lp = labels + (size_t)b * NA + a0;

#pragma unroll
    for (int i = 0; i < 2; ++i) {
        float fx = cx[i] * IMG_SZ, fy = cy[i] * IMG_SZ;
        float fw = cw[i] * IMG_SZ, fh = ch[i] * IMG_SZ;
        float hw = fw * 0.5f, hh = fh * 0.5f;
        bp[i] = make_float4(fx - hw, fy - hh, fx + hw, fy + hh);
        float s = (bs[i] > CONF) ? bs[i] : -1.0f;
        u32 fb = __float_as_uint(s);
        u32 u = (fb & 0x80000000u) ? ~fb : (fb | 0x80000000u);
        // 46-bit key: sortable score bits << 14 | inverted anchor index
        kp[i] = ((u64)u << 14) | (u64)(16383 - (a0 + i));
        lp[i] = bl[i];
    }
}

// ---------------- K2: per-batch radix-select + sort + NMS + output ----------
__global__ __launch_bounds__(NT)
void select_nms_kernel(const u64* __restrict__ keys,
                       const float4* __restrict__ boxes,
                       const int* __restrict__ labels,
                       float* __restrict__ out) {
    const int b = blockIdx.x;
    const int t = threadIdx.x;
    const int lane = t & 63, wid = t >> 6;

    __shared__ u64 skey[NT];                        // 8 KB   (bitonic exchange)
    __shared__ float offb[TOPK][4];                 // 16 KB  (offset boxes)
    __shared__ float area_s[TOPK];                  // 4 KB
    __shared__ unsigned char lb8[TOPK];             // 1 KB
    __shared__ unsigned char keep[TOPK];            // 1 KB
    __shared__ unsigned short rows[NCLS][64];       // 10 KB  (per-class rank lists)
    __shared__ int sh_hist[NCOPY * HPAD];           // 8.3 KB
    __shared__ int selB, selK, cnt, ktot_s;
    __shared__ int wsum[16], woff[16];

    // ---- load this batch's keys (<=9 per thread, stays in VGPRs) ----
    u64 kreg[KPT];
    const u64* kb = keys + (size_t)b * NA;
    int nk = 0;
    for (int i = t; i < NA; i += NT) kreg[nk++] = kb[i];

    // ---- 6-pass MSB-first radix select over the 46-bit key ----
    u64 P = 0ull;
    int kk = TOPK;
    for (int d = 5; d >= 0; --d) {
        for (int i = t; i < NCOPY * HPAD; i += NT) sh_hist[i] = 0;
        __syncthreads();
        u64 hmask = (~0ull) << (8 * (d + 1));
        int* myh = sh_hist + (wid & (NCOPY - 1)) * HPAD;
        for (int i = 0; i < KPT; ++i) {
            if (i < nk) {
                u64 key = kreg[i];
                if (((key ^ P) & hmask) == 0ull)
                    atomicAdd(&myh[(int)((key >> (8 * d)) & 255)], 1);
            }
        }
        __syncthreads();
        if (t < 64) {
            int h0 = 0, h1 = 0, h2 = 0, h3 = 0;
            for (int c = 0; c < NCOPY; ++c) {
                const int* hp = sh_hist + c * HPAD + 4 * t;   // 16B-aligned
                h0 += hp[0]; h1 += hp[1]; h2 += hp[2]; h3 += hp[3];
            }
            int s = h0 + h1 + h2 + h3;
            int S = s;                       // wave suffix-scan, no barriers
            #pragma unroll
            for (int off = 1; off < 64; off <<= 1) {
                int o = __shfl_down(S, off, 64);
                if (t + off < 64) S += o;
            }
            int Snext = S - s;
            int c3 = Snext + h3, c2 = c3 + h2, c1 = c2 + h1, c0 = c1 + h0;
            int cand = -1, above = 0;
            if (c0 >= kk) {
                if      (c3 >= kk) { cand = 4 * t + 3; above = Snext; }
                else if (c2 >= kk) { cand = 4 * t + 2; above = c3; }
                else if (c1 >= kk) { cand = 4 * t + 1; above = c2; }
                else               { cand = 4 * t;     above = c1; }
            }
            int pc = (cand < 0) ? 0 : (((cand + 1) << 16) | (kk - above));
            #pragma unroll
            for (int off = 32; off; off >>= 1)
                pc = max(pc, __shfl_down(pc, off, 64));
            if (t == 0) { selB = (pc >> 16) - 1; selK = pc & 0xFFFF; }
        }
        __syncthreads();
        P |= ((u64)selB) << (8 * d);
        kk = selK;
    }

    // ---- compact the exactly-TOPK keys >= P (wave-aggregated) ----
    if (t == 0) cnt = 0;
    __syncthreads();
    for (int i = 0; i < KPT; ++i) {
        bool p = (i < nk) && (kreg[i] >= P);
        u64 m = __ballot(p);
        int base = 0;
        if (lane == 0) base = atomicAdd(&cnt, (int)__popcll(m));
        base = __shfl(base, 0, 64);
        if (p) skey[base + (int)__popcll(m & ((1ull << lane) - 1ull))] = kreg[i];
    }
    if (t < NT - TOPK) skey[TOPK + t] = 0ull;
    __syncthreads();

    // ---- hybrid bitonic sort, descending: shfl_xor for stride<64 ----
    u64 myk = skey[t];
    for (int size = 2; size <= NT; size <<= 1) {
        bool up = ((t & size) == 0);
        for (int stride = size >> 1; stride; stride >>= 1) {
            u64 pk;
            if (stride >= 64) {
                __syncthreads(); skey[t] = myk; __syncthreads();
                pk = skey[t ^ stride];
            } else {
                pk = shflx64(myk, stride);
            }
            bool tlow = ((t & stride) == 0);
            u64 mn = (myk < pk) ? myk : pk;
            u64 mx = (myk < pk) ? pk : myk;
            myk = up ? (tlow ? mx : mn) : (tlow ? mn : mx);
        }
    }
    // myk == sorted skey[t]; kept in-register for gather and epilogue.

    // ---- gather payloads for sorted rank t ----
    int my_a = -1, my_L = 0;
    if (t < TOPK) {
        my_a = 16383 - (int)(myk & 16383ull);
        my_L = labels[(size_t)b * NA + my_a];
        lb8[t] = (unsigned char)my_L;
        float4 bx = boxes[(size_t)b * NA + my_a];
        float off = (float)my_L * MAX_WH;
        float ox0 = bx.x + off, oy0 = bx.y + off, ox1 = bx.z + off, oy1 = bx.w + off;
        offb[t][0] = ox0; offb[t][1] = oy0; offb[t][2] = ox1; offb[t][3] = oy1;
        area_s[t] = (ox1 - ox0) * (oy1 - oy0);   // ref: area on offset boxes
        keep[t] = 1;
    }
    __syncthreads();

    // ---- NMS: one wave per class; boxes in lane registers, no LDS in loop ----
    for (int c = wid; c < NCLS; c += 16) {
        // build this class's rank-ordered list via ballot compaction
        int n = 0;
        for (int chunk = 0; chunk < 16; ++chunk) {
            int j = chunk * 64 + lane;
            bool m = (j < TOPK) && (lb8[j] == (unsigned char)c);
            u64 bal = __ballot(m);
            if (m) {
                int pos = n + (int)__popcll(bal & ((1ull << lane) - 1ull));
                if (pos < 64) rows[c][pos] = (unsigned short)j;
            }
            n += (int)__popcll(bal);
        }
        if (n == 0) continue;
        if (n <= 64) {
            int j = (lane < n) ? (int)rows[c][lane] : (int)rows[c][0];
            float x0 = offb[j][0], y0 = offb[j][1];
            float x1 = offb[j][2], y1 = offb[j][3];
            float ar = area_s[j];
            u64 alive = (n >= 64) ? ~0ull : ((1ull << n) - 1ull);
            for (int i = 0; i < n; ++i) {
                if (!((alive >> i) & 1ull)) continue;
                float hx0 = __shfl(x0, i, 64);
                float hy0 = __shfl(y0, i, 64);
                float hx1 = __shfl(x1, i, 64);
                float hy1 = __shfl(y1, i, 64);
                float ha  = __shfl(ar, i, 64);
                float lx = fmaxf(hx0, x0), ly = fmaxf(hy0, y0);
                float rx = fminf(hx1, x1), ry = fminf(hy1, y1);
                float w = fmaxf(rx - lx, 0.0f);
                float h = fmaxf(ry - ly, 0.0f);
                float inter = w * h;
                float denom = ha + ar;
                denom = denom - inter;
                denom = denom + 1e-7f;
                bool sup = (lane > i) && (inter / denom > IOU_T);
                alive &= ~__ballot(sup);
            }
            if (lane < n) keep[j] = (unsigned char)((alive >> lane) & 1ull);
        } else if (lane == 0) {
            // general fallback (n > 64): serial greedy, exact order
            for (int i = 0; i < TOPK; ++i) {
                if (lb8[i] != (unsigned char)c || !keep[i]) continue;
                float ax0 = offb[i][0], ay0 = offb[i][1];
                float ax1 = offb[i][2], ay1 = offb[i][3];
                float aa = area_s[i];
                for (int j2 = i + 1; j2 < TOPK; ++j2) {
                    if (lb8[j2] != (unsigned char)c || !keep[j2]) continue;
                    float lx = fmaxf(ax0, offb[j2][0]);
                    float ly = fmaxf(ay0, offb[j2][1]);
                    float rx = fminf(ax1, offb[j2][2]);
                    float ry = fminf(ay1, offb[j2][3]);
                    float w = fmaxf(rx - lx, 0.0f);
                    float h = fmaxf(ry - ly, 0.0f);
                    float inter = w * h;
                    float denom = aa + area_s[j2];
                    denom = denom - inter;
                    denom = denom + 1e-7f;
                    if (inter / denom > IOU_T) keep[j2] = 0;
                }
            }
        }
    }
    __syncthreads();

    // ---- kept entries in sorted order ARE top_k(fin_s) order: ballot-scan ----
    bool valid = false;
    float sj = 0.0f;
    if (t < TOPK) {
        u32 u = (u32)(myk >> 14);
        u32 fb = (u & 0x80000000u) ? (u ^ 0x80000000u) : ~u;
        sj = __uint_as_float(fb);
        valid = keep[t] && (sj > CONF);
    }
    u64 m = __ballot(valid);
    if (lane == 0) wsum[wid] = (int)__popcll(m);
    __syncthreads();
    if (wid == 0) {
        int v = (lane < 16) ? wsum[lane] : 0;
        #pragma unroll
        for (int off = 1; off < 16; off <<= 1) {
            int o = __shfl_up(v, off, 64);
            if (lane >= off) v += o;
        }
        if (lane < 16) woff[lane] = v - wsum[lane];
        if (lane == 15) ktot_s = v;
    }
    __syncthreads();
    int ktot = ktot_s;
    int rank = woff[wid] + (int)__popcll(m & ((1ull << lane) - 1ull));

    float* out_boxes = out;
    float* out_scores = out + (size_t)BATCH * MAXDET * 4;
    float* out_labels = out + (size_t)BATCH * MAXDET * 5;
    if (valid && rank < MAXDET) {
        float4 bx = boxes[(size_t)b * NA + my_a];
        float* ob = out_boxes + ((size_t)b * MAXDET + rank) * 4;
        ob[0] = bx.x; ob[1] = bx.y; ob[2] = bx.z; ob[3] = bx.w;
        out_scores[(size_t)b * MAXDET + rank] = sj;
        out_labels[(size_t)b * MAXDET + rank] = coco_map_f[my_L];
    }
    if (t < MAXDET && t >= ktot) {
        float* ob = out_boxes + ((size_t)b * MAXDET + t) * 4;
        ob[0] = 0.0f; ob[1] = 0.0f; ob[2] = 0.0f; ob[3] = 0.0f;
        out_scores[(size_t)b * MAXDET + t] = 0.0f;
        out_labels[(size_t)b * MAXDET + t] = 0.0f;
    }
}

// ---------------------------------------------------------------------------
extern "C" void kernel_launch(void* const* d_in, const int* in_sizes, int n_in,
                              void* d_out, int out_size, void* d_ws, size_t ws_size,
                              hipStream_t stream) {
    const float* preds = (const float*)d_in[0];
    char* ws = (char*)d_ws;

    const size_t keys_bytes = (size_t)BATCH * NA * 8;    // 2,150,400
    const size_t boxes_bytes = (size_t)BATCH * NA * 16;  // 4,300,800

    u64* keys = (u64*)ws;
    float4* boxes = (float4*)(ws + keys_bytes);
    int* labels = (int*)(ws + keys_bytes + boxes_bytes);
    float* out = (float*)d_out;

    int total = BATCH * (NA / 2);
    decode_kernel<<<(total + 255) / 256, 256, 0, stream>>>(preds, keys, boxes, labels);
    select_nms_kernel<<<BATCH, NT, 0, stream>>>(keys, boxes, labels, out);
}